// Round 10
// baseline (252.431 us; speedup 1.0000x reference)
//
#include <hip/hip_runtime.h>
#include <hip/hip_bf16.h>

static constexpr int HEADS = 8;
static constexpr int D1 = 256;      // HEADS*HID
static constexpr int ODIM = 64;
static constexpr float NEG = 0.2f;

typedef __attribute__((ext_vector_type(8))) short bf16x8;
typedef __attribute__((ext_vector_type(8))) unsigned short u16x8;
typedef __attribute__((ext_vector_type(4))) float f32x4;

__device__ __forceinline__ float lrelu(float x) { return fmaxf(x, NEG * x); }
__device__ __forceinline__ float elu1(float x) { return x > 0.f ? x : expm1f(x); }

__device__ __forceinline__ unsigned short f2bf(float f) {
  unsigned u = __float_as_uint(f);
  unsigned r = (u + 0x7fffu + ((u >> 16) & 1u)) >> 16;
  return (unsigned short)r;
}
__device__ __forceinline__ float bf2f(unsigned short h) {
  return __uint_as_float((unsigned)h << 16);
}

__device__ __forceinline__ void gload_lds16(const void* g, void* l) {
  __builtin_amdgcn_global_load_lds(
      (const __attribute__((address_space(1))) void*)g,
      (__attribute__((address_space(3))) void*)l, 16, 0, 0);
}

// ---------------- hist (rank-capturing) + weight-prep (merged) ----------------
__global__ void k_hist_prep(const int* __restrict__ dst, int E, int TE,
                            int* __restrict__ deg, int* __restrict__ erank,
                            const float* __restrict__ W1, const float* __restrict__ W2,
                            unsigned short* __restrict__ BT1, unsigned short* __restrict__ B2T,
                            int HB) {
  int b = blockIdx.x;
  if (b < HB) {
    int i = b * 256 + threadIdx.x;
    if (i < TE) {
      int d = (i < E) ? __builtin_nontemporal_load(&dst[i]) : (i - E);
      int rk = atomicAdd(&deg[d], 1);   // rank within segment, fixes scatter order
      __builtin_nontemporal_store(rk, &erank[i]);
    }
  } else {
    int t = (b - HB) * 256 + threadIdx.x;
    if (t < 65536) {
      int k = t >> 8, nn = t & 255;
      BT1[nn * 256 + k] = f2bf(W1[t]);
    } else if (t < 65536 + 16384) {
      int t2 = t - 65536;
      int k = t2 >> 6, nn = t2 & 63;
      B2T[nn * 256 + k] = f2bf(W2[t2]);
    }
  }
}

// ---------------- single-launch exclusive scan (decoupled lookback) ----------------
__global__ void k_scan_lb(const int* __restrict__ deg, int n, int TE,
                          int* __restrict__ offs,
                          int* __restrict__ tstate, int* __restrict__ ticket) {
  __shared__ int sm[256];
  __shared__ int sh[2];  // [0]=tile, [1]=base
  if (threadIdx.x == 0) sh[0] = atomicAdd(ticket, 1);
  __syncthreads();
  const int tile = sh[0];
  int i = tile * 256 + threadIdx.x;
  int v = (i < n) ? deg[i] : 0;
  sm[threadIdx.x] = v;
  __syncthreads();
  for (int off = 1; off < 256; off <<= 1) {
    int t = (threadIdx.x >= off) ? sm[threadIdx.x - off] : 0;
    __syncthreads();
    sm[threadIdx.x] += t;
    __syncthreads();
  }
  const int total = sm[255];
  if (threadIdx.x == 0) {
    if (tile == 0) {
      __hip_atomic_store(&tstate[0], (2 << 24) | total, __ATOMIC_RELEASE,
                         __HIP_MEMORY_SCOPE_AGENT);
      sh[1] = 0;
    } else {
      __hip_atomic_store(&tstate[tile], (1 << 24) | total, __ATOMIC_RELEASE,
                         __HIP_MEMORY_SCOPE_AGENT);
    }
  }
  __syncthreads();
  if (tile != 0) {
    if (threadIdx.x < 64) {
      const int lane = threadIdx.x;
      int running = 0;
      int wstart = tile - 1;
      for (;;) {
        int idx = wstart - lane;
        int st = (idx >= 0)
                     ? __hip_atomic_load(&tstate[idx], __ATOMIC_ACQUIRE,
                                         __HIP_MEMORY_SCOPE_AGENT)
                     : (2 << 24);
        if (__ballot(st == 0)) continue;
        unsigned long long pref = __ballot((st >> 24) == 2);
        int contrib;
        if (pref) {
          int flane = (int)__ffsll(pref) - 1;
          contrib = (lane <= flane) ? (st & 0xFFFFFF) : 0;
        } else {
          contrib = st & 0xFFFFFF;
        }
#pragma unroll
        for (int off2 = 1; off2 < 64; off2 <<= 1) contrib += __shfl_xor(contrib, off2);
        running += contrib;
        if (pref) break;
        wstart -= 64;
      }
      if (lane == 0) {
        sh[1] = running;
        __hip_atomic_store(&tstate[tile], (2 << 24) | (running + total),
                           __ATOMIC_RELEASE, __HIP_MEMORY_SCOPE_AGENT);
      }
    }
    __syncthreads();
  }
  const int base = sh[1];
  if (i < n) offs[i] = base + sm[threadIdx.x] - v;
  if (i == 0) offs[n] = TE;
}

// ---------------- GEMM1 (1-term bf16, BN=256, x-prefetch) + fused alpha1 ∥ NT scatter ----
__global__ __launch_bounds__(512) void k_gemm1s(
    const float* __restrict__ X,            // [M][256]
    const unsigned short* __restrict__ BT,  // BT1 [256n][256k] (hi)
    const float* __restrict__ a_src, const float* __restrict__ a_dst,
    unsigned short* __restrict__ h1b,       // [Mpad][256]
    float* __restrict__ asrc, float* __restrict__ adst,
    int M, int Mblk,
    const int* __restrict__ src, const int* __restrict__ dst, int E, int TE,
    const int* __restrict__ offs, const int* __restrict__ erank,
    int* __restrict__ csr_src) {
  __shared__ __align__(128) char As[16384];   // [128r][128B] XOR-swizzled
  __shared__ __align__(128) char Bs[32768];   // [256c][128B] XOR-swizzled
  if (blockIdx.x >= Mblk) {
    // ---- scatter: pure non-temporal writes, no atomics ----
    int i = (blockIdx.x - Mblk) * 512 + threadIdx.x;
    if (i < TE) {
      int s, d;
      if (i < E) {
        s = __builtin_nontemporal_load(&src[i]);
        d = __builtin_nontemporal_load(&dst[i]);
      } else { s = i - E; d = i - E; }
      int rk = __builtin_nontemporal_load(&erank[i]);
      __builtin_nontemporal_store(s, &csr_src[offs[d] + rk]);
    }
    return;
  }
  const int tid = threadIdx.x;
  const int lane = tid & 63;
  const int wid = tid >> 6;
  const int bm = blockIdx.x * 128;
  const int wm = wid >> 2, wn = wid & 3;      // wave tile 64x64
  f32x4 acc[4][4] = {};
  float4 xv[2][2];
  auto loadX = [&](int kb) {
#pragma unroll
    for (int q = 0; q < 2; ++q) {
      int c = q * 512 + tid;
      int r = c >> 3, kc = c & 7;
      int gr = bm + r;
      xv[q][0] = make_float4(0.f, 0.f, 0.f, 0.f);
      xv[q][1] = xv[q][0];
      if (gr < M) {
        xv[q][0] = *(const float4*)&X[(size_t)gr * 256 + kb + kc * 8];
        xv[q][1] = *(const float4*)&X[(size_t)gr * 256 + kb + kc * 8 + 4];
      }
    }
  };
  loadX(0);
  for (int kb = 0; kb < 256; kb += 64) {
#pragma unroll
    for (int q = 0; q < 2; ++q) {
      int c = q * 512 + tid;
      int r = c >> 3, kc = c & 7;
      float vv[8] = {xv[q][0].x, xv[q][0].y, xv[q][0].z, xv[q][0].w,
                     xv[q][1].x, xv[q][1].y, xv[q][1].z, xv[q][1].w};
      u16x8 hv;
#pragma unroll
      for (int j = 0; j < 8; ++j) hv[j] = f2bf(vv[j]);
      *(u16x8*)(As + r * 128 + ((kc * 16) ^ ((r & 7) << 4))) = hv;
    }
#pragma unroll
    for (int q = 0; q < 4; ++q) {
      int c = q * 512 + tid;                   // chunk 0..2047
      int col = c >> 3;                        // 0..255
      int b = ((c & 7) * 16) ^ ((col & 7) << 4);
      gload_lds16(BT + (size_t)col * 256 + kb + (b >> 1),
                  Bs + (size_t)(q * 512 + (tid & ~63)) * 16);
    }
    __syncthreads();
    if (kb + 64 < 256) loadX(kb + 64);  // prefetch next x under MFMA
#pragma unroll
    for (int ks = 0; ks < 2; ++ks) {
      bf16x8 af[4], bfr[4];
      int bb = ks * 64 + (lane >> 4) * 16;
#pragma unroll
      for (int mi = 0; mi < 4; ++mi) {
        int row = wm * 64 + mi * 16 + (lane & 15);
        af[mi] = *(const bf16x8*)(As + row * 128 + (bb ^ ((row & 7) << 4)));
      }
#pragma unroll
      for (int ni = 0; ni < 4; ++ni) {
        int col = wn * 64 + ni * 16 + (lane & 15);
        bfr[ni] = *(const bf16x8*)(Bs + col * 128 + (bb ^ ((col & 7) << 4)));
      }
#pragma unroll
      for (int mi = 0; mi < 4; ++mi)
#pragma unroll
        for (int ni = 0; ni < 4; ++ni)
          acc[mi][ni] = __builtin_amdgcn_mfma_f32_16x16x32_bf16(af[mi], bfr[ni],
                                                                acc[mi][ni], 0, 0, 0);
    }
    __syncthreads();
  }
  // ---- epilogue: h1b write + fused alpha1 (heads 2wn, 2wn+1) ----
  const int h0 = 2 * wn, h1h = 2 * wn + 1;
  const int cl = lane & 15;
  const float as0 = a_src[h0 * 32 + cl],      ad0 = a_dst[h0 * 32 + cl];
  const float as1 = a_src[h0 * 32 + 16 + cl], ad1 = a_dst[h0 * 32 + 16 + cl];
  const float as2 = a_src[h1h * 32 + cl],      ad2 = a_dst[h1h * 32 + cl];
  const float as3 = a_src[h1h * 32 + 16 + cl], ad3 = a_dst[h1h * 32 + 16 + cl];
#pragma unroll
  for (int mi = 0; mi < 4; ++mi) {
    int gr0 = bm + wm * 64 + mi * 16 + (lane >> 4) * 4;
#pragma unroll
    for (int j = 0; j < 4; ++j) {
      int gr = gr0 + j;
#pragma unroll
      for (int ni = 0; ni < 4; ++ni) {
        int gc = wn * 64 + ni * 16 + cl;
        if (gr < M) h1b[(size_t)gr * 256 + gc] = f2bf(acc[mi][ni][j]);
      }
      float ps0 = acc[mi][0][j] * as0 + acc[mi][1][j] * as1;
      float pd0 = acc[mi][0][j] * ad0 + acc[mi][1][j] * ad1;
      float ps1 = acc[mi][2][j] * as2 + acc[mi][3][j] * as3;
      float pd1 = acc[mi][2][j] * ad2 + acc[mi][3][j] * ad3;
#pragma unroll
      for (int off = 1; off < 16; off <<= 1) {
        ps0 += __shfl_xor(ps0, off);
        pd0 += __shfl_xor(pd0, off);
        ps1 += __shfl_xor(ps1, off);
        pd1 += __shfl_xor(pd1, off);
      }
      if (cl == 0 && gr < M) {
        asrc[gr * 8 + h0] = ps0;
        adst[gr * 8 + h0] = pd0;
        asrc[gr * 8 + h1h] = ps1;
        adst[gr * 8 + h1h] = pd1;
      }
    }
  }
}

// ---------------- FUSED agg1 + gemm2 + alpha2 ----------------
// 256 threads = 4 waves; wave handles 16 dst nodes. Lane l: node = base+(l&15),
// k-chunk hi = l>>4. Gather layout IS the MFMA A-fragment layout:
// lane holds helu channels {kk*32 + hi*8 + j} of its node.
__global__ __launch_bounds__(256) void k_agg1f(
    const int* __restrict__ offs, const int* __restrict__ csr_src,
    const unsigned short* __restrict__ h1b,
    const float* __restrict__ asrc1, const float* __restrict__ adst1,
    const float* __restrict__ b1,
    const unsigned short* __restrict__ B2T,   // [64][256] hi(W2^T)
    const float* __restrict__ a_src2, const float* __restrict__ a_dst2,
    unsigned short* __restrict__ h2b,
    float* __restrict__ asrc2, float* __restrict__ adst2,
    int n) {
  const int tid = threadIdx.x;
  const int lane = tid & 63;
  const int wid = tid >> 6;
  const int nb = blockIdx.x * 64 + wid * 16;   // wave's node base
  const int hi = lane >> 4;                    // k-chunk group 0..3
  const int nt = lane & 15;                    // node-in-tile (= MFMA row / later col)
  const int node = nb + nt;
  const bool valid = node < n;
  int b = 0, e = 0;
  if (valid) { b = offs[node]; e = offs[node + 1]; }
  float ad[8];
  {
    int an = valid ? node : 0;
    float4 a0 = *(const float4*)&adst1[an * 8];
    float4 a1 = *(const float4*)&adst1[an * 8 + 4];
    ad[0] = a0.x; ad[1] = a0.y; ad[2] = a0.z; ad[3] = a0.w;
    ad[4] = a1.x; ad[5] = a1.y; ad[6] = a1.z; ad[7] = a1.w;
  }
  float ssum[8] = {};
  float acc[64] = {};   // [kk][j], static-indexed
  for (int it = 0;; ++it) {
    bool act = (b + it) < e;
    if (!__any(act)) break;
    if (act) {
      int s = csr_src[b + it];
      float4 s0 = *(const float4*)&asrc1[s * 8];
      float4 s1 = *(const float4*)&asrc1[s * 8 + 4];
      float asv[8] = {s0.x, s0.y, s0.z, s0.w, s1.x, s1.y, s1.z, s1.w};
      u16x8 r[8];
#pragma unroll
      for (int kk = 0; kk < 8; ++kk)
        r[kk] = *(const u16x8*)&h1b[(size_t)s * 256 + kk * 32 + hi * 8];
#pragma unroll
      for (int kk = 0; kk < 8; ++kk) {
        float w = __expf(lrelu(asv[kk] + ad[kk]));
        ssum[kk] += w;
#pragma unroll
        for (int j = 0; j < 8; ++j) acc[kk * 8 + j] += w * bf2f(r[kk][j]);
      }
    }
  }
  // helu (never materialized) -> bf16 MFMA A-fragments
  bf16x8 af[8];
#pragma unroll
  for (int kk = 0; kk < 8; ++kk) {
    float rr = ssum[kk] > 0.f ? 1.f / ssum[kk] : 0.f;
    int cb = kk * 32 + hi * 8;
    float4 b0 = *(const float4*)&b1[cb];
    float4 b1v = *(const float4*)&b1[cb + 4];
    float bb[8] = {b0.x, b0.y, b0.z, b0.w, b1v.x, b1v.y, b1v.z, b1v.w};
#pragma unroll
    for (int j = 0; j < 8; ++j)
      af[kk][j] = (short)f2bf(elu1(acc[kk * 8 + j] * rr + bb[j]));
  }
  // gemm2 tile: 16 rows x 64 cols, B fragments from L2-hot B2T
  f32x4 c2[4] = {};
#pragma unroll
  for (int kk = 0; kk < 8; ++kk) {
#pragma unroll
    for (int ni = 0; ni < 4; ++ni) {
      bf16x8 bf = *(const bf16x8*)&B2T[(size_t)(ni * 16 + nt) * 256 + kk * 32 + hi * 8];
      c2[ni] = __builtin_amdgcn_mfma_f32_16x16x32_bf16(af[kk], bf, c2[ni], 0, 0, 0);
    }
  }
  // epilogue: h2b write + fused alpha2 (C/D: col=lane&15, row=(lane>>4)*4+j)
  float a2s[4], a2d[4];
#pragma unroll
  for (int ni = 0; ni < 4; ++ni) {
    a2s[ni] = a_src2[ni * 16 + nt];
    a2d[ni] = a_dst2[ni * 16 + nt];
  }
#pragma unroll
  for (int j = 0; j < 4; ++j) {
    int row = nb + hi * 4 + j;
    bool rv = row < n;
    float ps = 0.f, pd = 0.f;
#pragma unroll
    for (int ni = 0; ni < 4; ++ni) {
      if (rv) h2b[(size_t)row * 64 + ni * 16 + nt] = f2bf(c2[ni][j]);
      ps += a2s[ni] * c2[ni][j];
      pd += a2d[ni] * c2[ni][j];
    }
#pragma unroll
    for (int off = 1; off < 16; off <<= 1) {
      ps += __shfl_xor(ps, off);
      pd += __shfl_xor(pd, off);
    }
    if (nt == 0 && rv) { asrc2[row] = ps; adst2[row] = pd; }
  }
}

// ---------------- layer-2 aggregation: 8 edge slots x 8 lanes, batched ----------------
__global__ void k_agg2(const int* __restrict__ offs, const int* __restrict__ csr_src,
                       const unsigned short* __restrict__ h2b, const float* __restrict__ asrc,
                       const float* __restrict__ adst, const float* __restrict__ b2,
                       int n, float* __restrict__ out) {
  int wave = (blockIdx.x * blockDim.x + threadIdx.x) >> 6;
  int lane = threadIdx.x & 63;
  if (wave >= n) return;
  int wv = __builtin_amdgcn_readfirstlane(wave);
  float ad = adst[wv];
  int b = offs[wv], e2 = offs[wv + 1];
  const int es = lane >> 3;  // edge slot 0..7
  const int cg = lane & 7;   // channel octet 0..7
  float ssum = 0.f;
  float acc[8] = {};
  int i = b;
  for (; i + 15 < e2; i += 16) {
    int s0 = csr_src[i + es], s1 = csr_src[i + 8 + es];
    u16x8 r0 = *(const u16x8*)&h2b[(size_t)s0 * ODIM + cg * 8];
    u16x8 r1 = *(const u16x8*)&h2b[(size_t)s1 * ODIM + cg * 8];
    float a0 = asrc[s0], a1 = asrc[s1];
    float w0 = __expf(lrelu(a0 + ad));
    float w1 = __expf(lrelu(a1 + ad));
    ssum += w0 + w1;
#pragma unroll
    for (int j = 0; j < 8; ++j) acc[j] += w0 * bf2f(r0[j]) + w1 * bf2f(r1[j]);
  }
  for (; i < e2; i += 8) {
    int idx = i + es;
    bool act = idx < e2;
    int s = csr_src[act ? idx : e2 - 1];
    u16x8 r = *(const u16x8*)&h2b[(size_t)s * ODIM + cg * 8];
    float w = act ? __expf(lrelu(asrc[s] + ad)) : 0.f;
    ssum += w;
#pragma unroll
    for (int j = 0; j < 8; ++j) acc[j] += w * bf2f(r[j]);
  }
#pragma unroll
  for (int off = 8; off < 64; off <<= 1) {
    ssum += __shfl_xor(ssum, off);
#pragma unroll
    for (int j = 0; j < 8; ++j) acc[j] += __shfl_xor(acc[j], off);
  }
  if (lane < 8) {
    float r = 1.f / ssum;
    float4 bb0 = *(const float4*)&b2[cg * 8];
    float4 bb1 = *(const float4*)&b2[cg * 8 + 4];
    float4 o0, o1;
    o0.x = acc[0] * r + bb0.x; o0.y = acc[1] * r + bb0.y;
    o0.z = acc[2] * r + bb0.z; o0.w = acc[3] * r + bb0.w;
    o1.x = acc[4] * r + bb1.x; o1.y = acc[5] * r + bb1.y;
    o1.z = acc[6] * r + bb1.z; o1.w = acc[7] * r + bb1.w;
    *(float4*)&out[(size_t)wave * ODIM + cg * 8] = o0;
    *(float4*)&out[(size_t)wave * ODIM + cg * 8 + 4] = o1;
  }
}

extern "C" void kernel_launch(void* const* d_in, const int* in_sizes, int n_in,
                              void* d_out, int out_size, void* d_ws, size_t ws_size,
                              hipStream_t stream) {
  const float* x      = (const float*)d_in[0];
  const int* eidx     = (const int*)d_in[1];
  const float* W1     = (const float*)d_in[2];
  const float* asrc1w = (const float*)d_in[3];
  const float* adst1w = (const float*)d_in[4];
  const float* b1     = (const float*)d_in[5];
  const float* W2     = (const float*)d_in[6];
  const float* asrc2w = (const float*)d_in[7];
  const float* adst2w = (const float*)d_in[8];
  const float* b2     = (const float*)d_in[9];
  float* out = (float*)d_out;

  const int N = in_sizes[0] / D1;     // 50000
  const int E = in_sizes[1] / 2;      // 800000
  const int TE = E + N;
  const int* src = eidx;
  const int* dst = eidx + E;
  const int Mblk = (N + 127) / 128;   // 391
  const int Mpad = Mblk * 128;        // 50048
  const int nb_n = (N + 255) / 256;   // 196
  const int nb_te = (TE + 255) / 256;
  const int nb_sc = (TE + 511) / 512; // scatter blocks (512 thr)
  const int nb_f  = (N + 63) / 64;    // fused agg1 blocks (64 nodes each)

  // ---- workspace carve-up ----
  char* ws = (char*)d_ws;
  size_t off = 0;
  auto carve = [&](size_t bytes) -> char* {
    char* p = ws + off;
    off = (off + bytes + 255) & ~(size_t)255;
    return p;
  };
  unsigned short* h1b  = (unsigned short*)carve((size_t)Mpad * D1 * 2);   // 25.6 MB
  unsigned short* h2b  = (unsigned short*)carve((size_t)N * ODIM * 2);    // 6.4 MB
  unsigned short* BT1  = (unsigned short*)carve((size_t)256 * 256 * 2);
  unsigned short* B2T2 = (unsigned short*)carve((size_t)64 * 256 * 2);
  float* asrc1 = (float*)carve((size_t)N * HEADS * 4);
  float* adst1 = (float*)carve((size_t)N * HEADS * 4);
  float* asrc2 = (float*)carve((size_t)N * 4);
  float* adst2 = (float*)carve((size_t)N * 4);
  // zero region: deg | tstate | ticket  (single memset)
  int* zr      = (int*)carve((size_t)(N + nb_n + 64) * 4);
  int* deg     = zr;
  int* tstate  = zr + N;
  int* ticket  = zr + N + nb_n;
  int* offs    = (int*)carve((size_t)(N + 1) * 4);
  int* erank   = (int*)carve((size_t)TE * 4);
  int* csr_src = (int*)carve((size_t)TE * 4);

  // ---- CSR build (hist captures ranks; scatter is atomic-free NT, overlapped with gemm1) ----
  hipMemsetAsync(zr, 0, (size_t)(N + nb_n + 1) * 4, stream);
  {
    const int HB = nb_te;
    const int PB = (65536 + 16384) / 256;  // 320 prep blocks
    k_hist_prep<<<HB + PB, 256, 0, stream>>>(dst, E, TE, deg, erank, W1, W2, BT1, B2T2, HB);
  }
  k_scan_lb<<<nb_n, 256, 0, stream>>>(deg, N, TE, offs, tstate, ticket);

  // ---- layer 1: GEMM + fused alpha1, overlapped with scatter ----
  k_gemm1s<<<Mblk + nb_sc, 512, 0, stream>>>(x, BT1, asrc1w, adst1w, h1b, asrc1, adst1,
                                             N, Mblk, src, dst, E, TE, offs, erank, csr_src);

  // ---- fused: agg1 + gemm2 + alpha2 (helu never materialized) ----
  k_agg1f<<<nb_f, 256, 0, stream>>>(offs, csr_src, h1b, asrc1, adst1, b1,
                                    B2T2, asrc2w, adst2w, h2b, asrc2, adst2, N);

  // ---- layer-2 aggregation ----
  k_agg2<<<(N + 3) / 4, 256, 0, stream>>>(offs, csr_src, h2b, asrc2, adst2, b2, N, out);
}

// Round 11
// 223.139 us; speedup vs baseline: 1.1313x; 1.1313x over previous
//
#include <hip/hip_runtime.h>
#include <hip/hip_bf16.h>

static constexpr int HEADS = 8;
static constexpr int D1 = 256;      // HEADS*HID
static constexpr int ODIM = 64;
static constexpr float NEG = 0.2f;

typedef __attribute__((ext_vector_type(8))) short bf16x8;
typedef __attribute__((ext_vector_type(8))) unsigned short u16x8;
typedef __attribute__((ext_vector_type(4))) float f32x4;

__device__ __forceinline__ float lrelu(float x) { return fmaxf(x, NEG * x); }
__device__ __forceinline__ float elu1(float x) { return x > 0.f ? x : expm1f(x); }

__device__ __forceinline__ unsigned short f2bf(float f) {
  unsigned u = __float_as_uint(f);
  unsigned r = (u + 0x7fffu + ((u >> 16) & 1u)) >> 16;
  return (unsigned short)r;
}
__device__ __forceinline__ float bf2f(unsigned short h) {
  return __uint_as_float((unsigned)h << 16);
}

__device__ __forceinline__ void gload_lds16(const void* g, void* l) {
  __builtin_amdgcn_global_load_lds(
      (const __attribute__((address_space(1))) void*)g,
      (__attribute__((address_space(3))) void*)l, 16, 0, 0);
}

// ---------------- hist (rank-capturing) + weight-prep (merged) ----------------
__global__ void k_hist_prep(const int* __restrict__ dst, int E, int TE,
                            int* __restrict__ deg, int* __restrict__ erank,
                            const float* __restrict__ W1, const float* __restrict__ W2,
                            unsigned short* __restrict__ BT1, unsigned short* __restrict__ B2T,
                            int HB) {
  int b = blockIdx.x;
  if (b < HB) {
    int i = b * 256 + threadIdx.x;
    if (i < TE) {
      int d = (i < E) ? __builtin_nontemporal_load(&dst[i]) : (i - E);
      int rk = atomicAdd(&deg[d], 1);   // rank within segment, fixes scatter order
      __builtin_nontemporal_store(rk, &erank[i]);
    }
  } else {
    int t = (b - HB) * 256 + threadIdx.x;
    if (t < 65536) {
      int k = t >> 8, nn = t & 255;
      BT1[nn * 256 + k] = f2bf(W1[t]);
    } else if (t < 65536 + 16384) {
      int t2 = t - 65536;
      int k = t2 >> 6, nn = t2 & 63;
      B2T[nn * 256 + k] = f2bf(W2[t2]);
    }
  }
}

// ---------------- single-launch exclusive scan (decoupled lookback) ----------------
__global__ void k_scan_lb(const int* __restrict__ deg, int n, int TE,
                          int* __restrict__ offs,
                          int* __restrict__ tstate, int* __restrict__ ticket) {
  __shared__ int sm[256];
  __shared__ int sh[2];  // [0]=tile, [1]=base
  if (threadIdx.x == 0) sh[0] = atomicAdd(ticket, 1);
  __syncthreads();
  const int tile = sh[0];
  int i = tile * 256 + threadIdx.x;
  int v = (i < n) ? deg[i] : 0;
  sm[threadIdx.x] = v;
  __syncthreads();
  for (int off = 1; off < 256; off <<= 1) {
    int t = (threadIdx.x >= off) ? sm[threadIdx.x - off] : 0;
    __syncthreads();
    sm[threadIdx.x] += t;
    __syncthreads();
  }
  const int total = sm[255];
  if (threadIdx.x == 0) {
    if (tile == 0) {
      __hip_atomic_store(&tstate[0], (2 << 24) | total, __ATOMIC_RELEASE,
                         __HIP_MEMORY_SCOPE_AGENT);
      sh[1] = 0;
    } else {
      __hip_atomic_store(&tstate[tile], (1 << 24) | total, __ATOMIC_RELEASE,
                         __HIP_MEMORY_SCOPE_AGENT);
    }
  }
  __syncthreads();
  if (tile != 0) {
    if (threadIdx.x < 64) {
      const int lane = threadIdx.x;
      int running = 0;
      int wstart = tile - 1;
      for (;;) {
        int idx = wstart - lane;
        int st = (idx >= 0)
                     ? __hip_atomic_load(&tstate[idx], __ATOMIC_ACQUIRE,
                                         __HIP_MEMORY_SCOPE_AGENT)
                     : (2 << 24);
        if (__ballot(st == 0)) continue;
        unsigned long long pref = __ballot((st >> 24) == 2);
        int contrib;
        if (pref) {
          int flane = (int)__ffsll(pref) - 1;
          contrib = (lane <= flane) ? (st & 0xFFFFFF) : 0;
        } else {
          contrib = st & 0xFFFFFF;
        }
#pragma unroll
        for (int off2 = 1; off2 < 64; off2 <<= 1) contrib += __shfl_xor(contrib, off2);
        running += contrib;
        if (pref) break;
        wstart -= 64;
      }
      if (lane == 0) {
        sh[1] = running;
        __hip_atomic_store(&tstate[tile], (2 << 24) | (running + total),
                           __ATOMIC_RELEASE, __HIP_MEMORY_SCOPE_AGENT);
      }
    }
    __syncthreads();
  }
  const int base = sh[1];
  if (i < n) offs[i] = base + sm[threadIdx.x] - v;
  if (i == 0) offs[n] = TE;
}

// ---------------- GEMM1 (1-term bf16, BN=256, x-prefetch) + fused alpha1 ∥ NT scatter ----
__global__ __launch_bounds__(512) void k_gemm1s(
    const float* __restrict__ X,            // [M][256]
    const unsigned short* __restrict__ BT,  // BT1 [256n][256k] (hi)
    const float* __restrict__ a_src, const float* __restrict__ a_dst,
    unsigned short* __restrict__ h1b,       // [Mpad][256]
    float* __restrict__ asrc, float* __restrict__ adst,
    int M, int Mblk,
    const int* __restrict__ src, const int* __restrict__ dst, int E, int TE,
    const int* __restrict__ offs, const int* __restrict__ erank,
    int* __restrict__ csr_src) {
  __shared__ __align__(128) char As[16384];   // [128r][128B] XOR-swizzled
  __shared__ __align__(128) char Bs[32768];   // [256c][128B] XOR-swizzled
  if (blockIdx.x >= Mblk) {
    // ---- scatter: pure non-temporal writes, no atomics ----
    int i = (blockIdx.x - Mblk) * 512 + threadIdx.x;
    if (i < TE) {
      int s, d;
      if (i < E) {
        s = __builtin_nontemporal_load(&src[i]);
        d = __builtin_nontemporal_load(&dst[i]);
      } else { s = i - E; d = i - E; }
      int rk = __builtin_nontemporal_load(&erank[i]);
      __builtin_nontemporal_store(s, &csr_src[offs[d] + rk]);
    }
    return;
  }
  const int tid = threadIdx.x;
  const int lane = tid & 63;
  const int wid = tid >> 6;
  const int bm = blockIdx.x * 128;
  const int wm = wid >> 2, wn = wid & 3;      // wave tile 64x64
  f32x4 acc[4][4] = {};
  float4 xv[2][2];
  auto loadX = [&](int kb) {
#pragma unroll
    for (int q = 0; q < 2; ++q) {
      int c = q * 512 + tid;
      int r = c >> 3, kc = c & 7;
      int gr = bm + r;
      xv[q][0] = make_float4(0.f, 0.f, 0.f, 0.f);
      xv[q][1] = xv[q][0];
      if (gr < M) {
        xv[q][0] = *(const float4*)&X[(size_t)gr * 256 + kb + kc * 8];
        xv[q][1] = *(const float4*)&X[(size_t)gr * 256 + kb + kc * 8 + 4];
      }
    }
  };
  loadX(0);
  for (int kb = 0; kb < 256; kb += 64) {
#pragma unroll
    for (int q = 0; q < 2; ++q) {
      int c = q * 512 + tid;
      int r = c >> 3, kc = c & 7;
      float vv[8] = {xv[q][0].x, xv[q][0].y, xv[q][0].z, xv[q][0].w,
                     xv[q][1].x, xv[q][1].y, xv[q][1].z, xv[q][1].w};
      u16x8 hv;
#pragma unroll
      for (int j = 0; j < 8; ++j) hv[j] = f2bf(vv[j]);
      *(u16x8*)(As + r * 128 + ((kc * 16) ^ ((r & 7) << 4))) = hv;
    }
#pragma unroll
    for (int q = 0; q < 4; ++q) {
      int c = q * 512 + tid;                   // chunk 0..2047
      int col = c >> 3;                        // 0..255
      int b = ((c & 7) * 16) ^ ((col & 7) << 4);
      gload_lds16(BT + (size_t)col * 256 + kb + (b >> 1),
                  Bs + (size_t)(q * 512 + (tid & ~63)) * 16);
    }
    __syncthreads();
    if (kb + 64 < 256) loadX(kb + 64);  // prefetch next x under MFMA
#pragma unroll
    for (int ks = 0; ks < 2; ++ks) {
      bf16x8 af[4], bfr[4];
      int bb = ks * 64 + (lane >> 4) * 16;
#pragma unroll
      for (int mi = 0; mi < 4; ++mi) {
        int row = wm * 64 + mi * 16 + (lane & 15);
        af[mi] = *(const bf16x8*)(As + row * 128 + (bb ^ ((row & 7) << 4)));
      }
#pragma unroll
      for (int ni = 0; ni < 4; ++ni) {
        int col = wn * 64 + ni * 16 + (lane & 15);
        bfr[ni] = *(const bf16x8*)(Bs + col * 128 + (bb ^ ((col & 7) << 4)));
      }
#pragma unroll
      for (int mi = 0; mi < 4; ++mi)
#pragma unroll
        for (int ni = 0; ni < 4; ++ni)
          acc[mi][ni] = __builtin_amdgcn_mfma_f32_16x16x32_bf16(af[mi], bfr[ni],
                                                                acc[mi][ni], 0, 0, 0);
    }
    __syncthreads();
  }
  // ---- epilogue: h1b write + fused alpha1 (heads 2wn, 2wn+1) ----
  const int h0 = 2 * wn, h1h = 2 * wn + 1;
  const int cl = lane & 15;
  const float as0 = a_src[h0 * 32 + cl],      ad0 = a_dst[h0 * 32 + cl];
  const float as1 = a_src[h0 * 32 + 16 + cl], ad1 = a_dst[h0 * 32 + 16 + cl];
  const float as2 = a_src[h1h * 32 + cl],      ad2 = a_dst[h1h * 32 + cl];
  const float as3 = a_src[h1h * 32 + 16 + cl], ad3 = a_dst[h1h * 32 + 16 + cl];
#pragma unroll
  for (int mi = 0; mi < 4; ++mi) {
    int gr0 = bm + wm * 64 + mi * 16 + (lane >> 4) * 4;
#pragma unroll
    for (int j = 0; j < 4; ++j) {
      int gr = gr0 + j;
#pragma unroll
      for (int ni = 0; ni < 4; ++ni) {
        int gc = wn * 64 + ni * 16 + cl;
        if (gr < M) h1b[(size_t)gr * 256 + gc] = f2bf(acc[mi][ni][j]);
      }
      float ps0 = acc[mi][0][j] * as0 + acc[mi][1][j] * as1;
      float pd0 = acc[mi][0][j] * ad0 + acc[mi][1][j] * ad1;
      float ps1 = acc[mi][2][j] * as2 + acc[mi][3][j] * as3;
      float pd1 = acc[mi][2][j] * ad2 + acc[mi][3][j] * ad3;
#pragma unroll
      for (int off = 1; off < 16; off <<= 1) {
        ps0 += __shfl_xor(ps0, off);
        pd0 += __shfl_xor(pd0, off);
        ps1 += __shfl_xor(ps1, off);
        pd1 += __shfl_xor(pd1, off);
      }
      if (cl == 0 && gr < M) {
        asrc[gr * 8 + h0] = ps0;
        adst[gr * 8 + h0] = pd0;
        asrc[gr * 8 + h1h] = ps1;
        adst[gr * 8 + h1h] = pd1;
      }
    }
  }
}

// ---------------- FUSED agg1 + gemm2 + alpha2 (v2: TLP-preserving) ----------------
// 512 threads = 8 waves; block handles 16 nodes; each wave aggregates 2 nodes
// SEQUENTIALLY with the proven round-9 pattern (2 edge slots x 32 lanes, u16x8).
// Aggregated bf16 helu rows -> LDS; waves 0..3 then run the 16x64 gemm2 tile.
__global__ __launch_bounds__(512, 4) void k_agg1f(
    const int* __restrict__ offs, const int* __restrict__ csr_src,
    const unsigned short* __restrict__ h1b,
    const float* __restrict__ asrc1, const float* __restrict__ adst1,
    const float* __restrict__ b1,
    const unsigned short* __restrict__ B2T,   // [64][256] hi(W2^T)
    const float* __restrict__ a_src2, const float* __restrict__ a_dst2,
    unsigned short* __restrict__ h2b,
    float* __restrict__ asrc2, float* __restrict__ adst2,
    int n) {
  __shared__ unsigned short hl[16][264];   // +8 shorts pad -> 2-way-free reads
  __shared__ float red[4][16][2];
  const int tid = threadIdx.x;
  const int lane = tid & 63;
  const int wid = tid >> 6;                // 0..7
  const int nbase = blockIdx.x * 16;
  const int es = lane >> 5;                // edge slot 0..1
  const int cg = lane & 31;                // channel octet 0..31
  const int hh = cg >> 2;                  // head
  // ---- phase 1: aggregate 2 nodes per wave (round-9 engine) ----
#pragma unroll
  for (int t = 0; t < 2; ++t) {
    const int nrow = wid * 2 + t;
    const int node = nbase + nrow;
    const bool valid = node < n;
    int b = 0, e2 = 0;
    float ad = 0.f;
    if (valid) {
      b = offs[node];
      e2 = offs[node + 1];
      ad = adst1[node * 8 + hh];
    }
    float ssum = 0.f;
    float acc[8] = {};
    int i = b;
    for (; i + 7 < e2; i += 8) {
      int s[4];
#pragma unroll
      for (int u = 0; u < 4; ++u) s[u] = csr_src[i + 2 * u + es];
      u16x8 r[4];
      float as_[4];
#pragma unroll
      for (int u = 0; u < 4; ++u) {
        r[u] = *(const u16x8*)&h1b[(size_t)s[u] * D1 + cg * 8];
        as_[u] = asrc1[s[u] * 8 + hh];
      }
#pragma unroll
      for (int u = 0; u < 4; ++u) {
        float w = __expf(lrelu(as_[u] + ad));
        ssum += w;
#pragma unroll
        for (int j = 0; j < 8; ++j) acc[j] += w * bf2f(r[u][j]);
      }
    }
    for (; i < e2; i += 2) {
      int idx = i + es;
      bool act = idx < e2;
      int s = csr_src[act ? idx : e2 - 1];
      u16x8 r = *(const u16x8*)&h1b[(size_t)s * D1 + cg * 8];
      float w = act ? __expf(lrelu(asrc1[s * 8 + hh] + ad)) : 0.f;
      ssum += w;
#pragma unroll
      for (int j = 0; j < 8; ++j) acc[j] += w * bf2f(r[j]);
    }
    ssum += __shfl_xor(ssum, 32);
#pragma unroll
    for (int j = 0; j < 8; ++j) acc[j] += __shfl_xor(acc[j], 32);
    if (lane < 32) {
      float rr = (valid && ssum > 0.f) ? 1.f / ssum : 0.f;
      float4 bb0 = *(const float4*)&b1[cg * 8];
      float4 bb1 = *(const float4*)&b1[cg * 8 + 4];
      float bbv[8] = {bb0.x, bb0.y, bb0.z, bb0.w, bb1.x, bb1.y, bb1.z, bb1.w};
      u16x8 o;
#pragma unroll
      for (int j = 0; j < 8; ++j)
        o[j] = valid ? f2bf(elu1(acc[j] * rr + bbv[j])) : (unsigned short)0;
      *(u16x8*)&hl[nrow][cg * 8] = o;
    }
  }
  __syncthreads();
  // ---- phase 2: gemm2 16x64 tile (waves 0..3, ni = wid) + fused alpha2 ----
  if (wid < 4) {
    const int hi = lane >> 4;    // k-group 0..3
    const int nt = lane & 15;    // A-row (node) / B-col index
    f32x4 c2 = {};
#pragma unroll
    for (int kk = 0; kk < 8; ++kk) {
      bf16x8 a = *(const bf16x8*)&hl[nt][kk * 32 + hi * 8];
      bf16x8 bv = *(const bf16x8*)&B2T[(size_t)(wid * 16 + nt) * 256 + kk * 32 + hi * 8];
      c2 = __builtin_amdgcn_mfma_f32_16x16x32_bf16(a, bv, c2, 0, 0, 0);
    }
    const int col = wid * 16 + nt;
    const float sA = a_src2[col], sD = a_dst2[col];
    float psj[4], pdj[4];
#pragma unroll
    for (int j = 0; j < 4; ++j) {
      int node = nbase + hi * 4 + j;
      if (node < n) h2b[(size_t)node * 64 + col] = f2bf(c2[j]);
      psj[j] = sA * c2[j];
      pdj[j] = sD * c2[j];
    }
#pragma unroll
    for (int off = 1; off < 16; off <<= 1) {
#pragma unroll
      for (int j = 0; j < 4; ++j) {
        psj[j] += __shfl_xor(psj[j], off);
        pdj[j] += __shfl_xor(pdj[j], off);
      }
    }
    if (nt == 0) {
#pragma unroll
      for (int j = 0; j < 4; ++j) {
        red[wid][hi * 4 + j][0] = psj[j];
        red[wid][hi * 4 + j][1] = pdj[j];
      }
    }
  }
  __syncthreads();
  if (tid < 16) {
    int node = nbase + tid;
    if (node < n) {
      asrc2[node] = red[0][tid][0] + red[1][tid][0] + red[2][tid][0] + red[3][tid][0];
      adst2[node] = red[0][tid][1] + red[1][tid][1] + red[2][tid][1] + red[3][tid][1];
    }
  }
}

// ---------------- layer-2 aggregation: 8 edge slots x 8 lanes, batched ----------------
__global__ void k_agg2(const int* __restrict__ offs, const int* __restrict__ csr_src,
                       const unsigned short* __restrict__ h2b, const float* __restrict__ asrc,
                       const float* __restrict__ adst, const float* __restrict__ b2,
                       int n, float* __restrict__ out) {
  int wave = (blockIdx.x * blockDim.x + threadIdx.x) >> 6;
  int lane = threadIdx.x & 63;
  if (wave >= n) return;
  int wv = __builtin_amdgcn_readfirstlane(wave);
  float ad = adst[wv];
  int b = offs[wv], e2 = offs[wv + 1];
  const int es = lane >> 3;  // edge slot 0..7
  const int cg = lane & 7;   // channel octet 0..7
  float ssum = 0.f;
  float acc[8] = {};
  int i = b;
  for (; i + 15 < e2; i += 16) {
    int s0 = csr_src[i + es], s1 = csr_src[i + 8 + es];
    u16x8 r0 = *(const u16x8*)&h2b[(size_t)s0 * ODIM + cg * 8];
    u16x8 r1 = *(const u16x8*)&h2b[(size_t)s1 * ODIM + cg * 8];
    float a0 = asrc[s0], a1 = asrc[s1];
    float w0 = __expf(lrelu(a0 + ad));
    float w1 = __expf(lrelu(a1 + ad));
    ssum += w0 + w1;
#pragma unroll
    for (int j = 0; j < 8; ++j) acc[j] += w0 * bf2f(r0[j]) + w1 * bf2f(r1[j]);
  }
  for (; i < e2; i += 8) {
    int idx = i + es;
    bool act = idx < e2;
    int s = csr_src[act ? idx : e2 - 1];
    u16x8 r = *(const u16x8*)&h2b[(size_t)s * ODIM + cg * 8];
    float w = act ? __expf(lrelu(asrc[s] + ad)) : 0.f;
    ssum += w;
#pragma unroll
    for (int j = 0; j < 8; ++j) acc[j] += w * bf2f(r[j]);
  }
#pragma unroll
  for (int off = 8; off < 64; off <<= 1) {
    ssum += __shfl_xor(ssum, off);
#pragma unroll
    for (int j = 0; j < 8; ++j) acc[j] += __shfl_xor(acc[j], off);
  }
  if (lane < 8) {
    float r = 1.f / ssum;
    float4 bb0 = *(const float4*)&b2[cg * 8];
    float4 bb1 = *(const float4*)&b2[cg * 8 + 4];
    float4 o0, o1;
    o0.x = acc[0] * r + bb0.x; o0.y = acc[1] * r + bb0.y;
    o0.z = acc[2] * r + bb0.z; o0.w = acc[3] * r + bb0.w;
    o1.x = acc[4] * r + bb1.x; o1.y = acc[5] * r + bb1.y;
    o1.z = acc[6] * r + bb1.z; o1.w = acc[7] * r + bb1.w;
    *(float4*)&out[(size_t)wave * ODIM + cg * 8] = o0;
    *(float4*)&out[(size_t)wave * ODIM + cg * 8 + 4] = o1;
  }
}

extern "C" void kernel_launch(void* const* d_in, const int* in_sizes, int n_in,
                              void* d_out, int out_size, void* d_ws, size_t ws_size,
                              hipStream_t stream) {
  const float* x      = (const float*)d_in[0];
  const int* eidx     = (const int*)d_in[1];
  const float* W1     = (const float*)d_in[2];
  const float* asrc1w = (const float*)d_in[3];
  const float* adst1w = (const float*)d_in[4];
  const float* b1     = (const float*)d_in[5];
  const float* W2     = (const float*)d_in[6];
  const float* asrc2w = (const float*)d_in[7];
  const float* adst2w = (const float*)d_in[8];
  const float* b2     = (const float*)d_in[9];
  float* out = (float*)d_out;

  const int N = in_sizes[0] / D1;     // 50000
  const int E = in_sizes[1] / 2;      // 800000
  const int TE = E + N;
  const int* src = eidx;
  const int* dst = eidx + E;
  const int Mblk = (N + 127) / 128;   // 391
  const int Mpad = Mblk * 128;        // 50048
  const int nb_n = (N + 255) / 256;   // 196
  const int nb_te = (TE + 255) / 256;
  const int nb_sc = (TE + 511) / 512; // scatter blocks (512 thr)
  const int nb_f  = (N + 15) / 16;    // fused agg1 blocks (16 nodes each)

  // ---- workspace carve-up ----
  char* ws = (char*)d_ws;
  size_t off = 0;
  auto carve = [&](size_t bytes) -> char* {
    char* p = ws + off;
    off = (off + bytes + 255) & ~(size_t)255;
    return p;
  };
  unsigned short* h1b  = (unsigned short*)carve((size_t)Mpad * D1 * 2);   // 25.6 MB
  unsigned short* h2b  = (unsigned short*)carve((size_t)N * ODIM * 2);    // 6.4 MB
  unsigned short* BT1  = (unsigned short*)carve((size_t)256 * 256 * 2);
  unsigned short* B2T2 = (unsigned short*)carve((size_t)64 * 256 * 2);
  float* asrc1 = (float*)carve((size_t)N * HEADS * 4);
  float* adst1 = (float*)carve((size_t)N * HEADS * 4);
  float* asrc2 = (float*)carve((size_t)N * 4);
  float* adst2 = (float*)carve((size_t)N * 4);
  // zero region: deg | tstate | ticket  (single memset)
  int* zr      = (int*)carve((size_t)(N + nb_n + 64) * 4);
  int* deg     = zr;
  int* tstate  = zr + N;
  int* ticket  = zr + N + nb_n;
  int* offs    = (int*)carve((size_t)(N + 1) * 4);
  int* erank   = (int*)carve((size_t)TE * 4);
  int* csr_src = (int*)carve((size_t)TE * 4);

  // ---- CSR build (hist captures ranks; scatter is atomic-free NT, overlapped with gemm1) ----
  hipMemsetAsync(zr, 0, (size_t)(N + nb_n + 1) * 4, stream);
  {
    const int HB = nb_te;
    const int PB = (65536 + 16384) / 256;  // 320 prep blocks
    k_hist_prep<<<HB + PB, 256, 0, stream>>>(dst, E, TE, deg, erank, W1, W2, BT1, B2T2, HB);
  }
  k_scan_lb<<<nb_n, 256, 0, stream>>>(deg, N, TE, offs, tstate, ticket);

  // ---- layer 1: GEMM + fused alpha1, overlapped with scatter ----
  k_gemm1s<<<Mblk + nb_sc, 512, 0, stream>>>(x, BT1, asrc1w, adst1w, h1b, asrc1, adst1,
                                             N, Mblk, src, dst, E, TE, offs, erank, csr_src);

  // ---- fused: agg1 (round-9 engine) + gemm2 + alpha2 ----
  k_agg1f<<<nb_f, 512, 0, stream>>>(offs, csr_src, h1b, asrc1, adst1, b1,
                                    B2T2, asrc2w, adst2w, h2b, asrc2, adst2, N);

  // ---- layer-2 aggregation ----
  k_agg2<<<(N + 3) / 4, 256, 0, stream>>>(offs, csr_src, h2b, asrc2, adst2, b2, N, out);
}